// Round 8
// baseline (27.973 us; speedup 1.0000x reference)
//
#include <hip/hip_runtime.h>

#define TLEN 1461
#define L2E      1.44269504088896340736f
#define TWO_L2E  2.88539008177792681472f

typedef __bf16 bf16x8 __attribute__((ext_vector_type(8)));
typedef float f32x16 __attribute__((ext_vector_type(16)));

union FragU { unsigned u[4]; bf16x8 f; };

__device__ __forceinline__ float step_fn(float x) {
    // (tanh(5x)+1)/2 = sigmoid(10x) = 1/(1+exp2(-10*log2e*x))
    float e = __builtin_amdgcn_exp2f(x * -14.4269504088896341f);
    return __builtin_amdgcn_rcpf(1.0f + e);
}
__device__ __forceinline__ unsigned cvt_pk_bf16(float lo, float hi) {
    unsigned r;
    asm("v_cvt_pk_bf16_f32 %0, %1, %2" : "=v"(r) : "v"(lo), "v"(hi));
    return r;
}
__device__ __forceinline__ void plswap(unsigned &a, unsigned &b) {
    asm("v_permlane32_swap_b32 %0, %1" : "+v"(a), "+v"(b));
}
__device__ __forceinline__ float plswap_add(float a, float b) {
    unsigned ua = __float_as_uint(a), ub = __float_as_uint(b);
    plswap(ua, ub);
    return __uint_as_float(ua) + __uint_as_float(ub);
}

// 4 pre-activations y=2*log2e*x -> tanh via SHARED rcp (1 rcp per 4 sigmas)
// -> 2 packed bf16 words. y clamped to +-30 (tanh saturated, overflow-proof).
__device__ __forceinline__ void quad_tanh_pack(float y0, float y1, float y2, float y3,
                                               unsigned &wlo, unsigned &whi) {
    y0 = fminf(fmaxf(y0, -30.0f), 30.0f);
    y1 = fminf(fmaxf(y1, -30.0f), 30.0f);
    y2 = fminf(fmaxf(y2, -30.0f), 30.0f);
    y3 = fminf(fmaxf(y3, -30.0f), 30.0f);
    float d0 = 1.0f + __builtin_amdgcn_exp2f(y0);
    float d1 = 1.0f + __builtin_amdgcn_exp2f(y1);
    float d2 = 1.0f + __builtin_amdgcn_exp2f(y2);
    float d3 = 1.0f + __builtin_amdgcn_exp2f(y3);
    float Pab = d0 * d1, Pcd = d2 * d3;
    float R = __builtin_amdgcn_rcpf(Pab * Pcd);
    float RPcd = Pcd * R, RPab = Pab * R;      // = 1/(d0 d1), 1/(d2 d3)
    float h0 = fmaf(-2.0f * d1, RPcd, 1.0f);   // 1 - 2*sigma0
    float h1 = fmaf(-2.0f * d0, RPcd, 1.0f);
    float h2 = fmaf(-2.0f * d3, RPab, 1.0f);
    float h3 = fmaf(-2.0f * d2, RPab, 1.0f);
    wlo = cvt_pk_bf16(h0, h1);
    whi = cvt_pk_bf16(h2, h3);
}
// oops: h = 1-2*sigma with sigma0 = d1*Pcd*R -> -2*d1 needs a mul; use fma chain:
// (rewritten inline below as t=d*RP then fma(-2,t,1) to keep it 2 ops)

// weighted sigma quad for the tail dot: returns sum_i w[i]*sigma(y[i])
// via one rcp. No clamps: |y| <= ~13 here, product <= 2^52.
__device__ __forceinline__ float quad_wsum_sigma(float y0, float y1, float y2, float y3,
                                                 float w0, float w1, float w2, float w3) {
    float d0 = 1.0f + __builtin_amdgcn_exp2f(y0);
    float d1 = 1.0f + __builtin_amdgcn_exp2f(y1);
    float d2 = 1.0f + __builtin_amdgcn_exp2f(y2);
    float d3 = 1.0f + __builtin_amdgcn_exp2f(y3);
    float Pab = d0 * d1, Pcd = d2 * d3;
    float R = __builtin_amdgcn_rcpf(Pab * Pcd);
    float N1 = fmaf(w1, d0, w0 * d1);          // w0/d0 + w1/d1 numerator over Pab
    float N2 = fmaf(w3, d2, w2 * d3);
    float N  = fmaf(N2, Pab, N1 * Pcd);
    return N * R;
}

// layer2 MFMA (combined A: ET rows 0-15, Q rows 16-31) + shared-rcp sigma dot.
// Weight constants rematerializable (uniform s_load + cndmask on hi).
template <int BASE>
__device__ __forceinline__ float tail_slim(const FragU a2,
    const float* __restrict__ b2, const float* __restrict__ w3,
    float pinit, bool hi, const FragU ba, const FragU bb)
{
    f32x16 c0, c1;
#pragma unroll
    for (int r = 0; r < 8; ++r) {
        const int j0 = (r & 3) + 8 * (r >> 2);
        float jb = TWO_L2E * (hi ? b2[j0 + 4] : b2[j0]);
        c0[BASE + r] = jb;
        c1[BASE + r] = jb;
    }
    c0 = __builtin_amdgcn_mfma_f32_32x32x16_bf16(a2.f, ba.f, c0, 0, 0, 0);
    c1 = __builtin_amdgcn_mfma_f32_32x32x16_bf16(a2.f, bb.f, c1, 0, 0, 0);

    float w3n[8];
#pragma unroll
    for (int r = 0; r < 8; ++r) {
        const int j0 = (r & 3) + 8 * (r >> 2);
        w3n[r] = -2.0f * L2E * (hi ? w3[j0 + 4] : w3[j0]);
    }
    float p0 = pinit, p1 = pinit;
    p0 += quad_wsum_sigma(c0[BASE + 0], c0[BASE + 1], c0[BASE + 2], c0[BASE + 3],
                          w3n[0], w3n[1], w3n[2], w3n[3]);
    p0 += quad_wsum_sigma(c0[BASE + 4], c0[BASE + 5], c0[BASE + 6], c0[BASE + 7],
                          w3n[4], w3n[5], w3n[6], w3n[7]);
    p1 += quad_wsum_sigma(c1[BASE + 0], c1[BASE + 1], c1[BASE + 2], c1[BASE + 3],
                          w3n[0], w3n[1], w3n[2], w3n[3]);
    p1 += quad_wsum_sigma(c1[BASE + 4], c1[BASE + 5], c1[BASE + 6], c1[BASE + 7],
                          w3n[4], w3n[5], w3n[6], w3n[7]);
    return plswap_add(p0, p1);
}

__device__ __forceinline__ float2 sample_pipeline(
    float tv, float S_snow, float S_water,
    const float4* __restrict__ s_tbl, const FragU a2,
    float pinit_e, float pinit_q, bool hi,
    float Df, float Tmax, float Tmin,
    const float* __restrict__ g_ew1, const float* __restrict__ g_eb1,
    const float* __restrict__ g_eb2, const float* __restrict__ g_ew3,
    const float* __restrict__ g_qw1, const float* __restrict__ g_qb1,
    const float* __restrict__ g_qb2, const float* __restrict__ g_qw3)
{
    int idx = (int)tv;
    idx = max(0, min(idx, TLEN - 2));
    const float fr = tv - (float)idx;
    const float4 t0 = s_tbl[idx];
    const float4 t1 = s_tbl[idx + 1];
    const float precp = fmaf(fr, t1.x - t0.x, t0.x);
    const float temp  = fmaf(fr, t1.y - t0.y, t0.y);
    const float lday  = fmaf(fr, t1.z - t0.z, t0.z);

    // ===== layer1 (fp32, sample-major), shared-rcp quad tanh -> pack =====
    unsigned elo[4], ehi[4], qlo[4], qhi[4];
#pragma unroll
    for (int j4 = 0; j4 < 4; ++j4) {
        float4 b4 = *reinterpret_cast<const float4*>(&g_eb1[j4 * 4]);
        float4 w0 = *reinterpret_cast<const float4*>(&g_ew1[0 * 16 + j4 * 4]);
        float4 w1 = *reinterpret_cast<const float4*>(&g_ew1[1 * 16 + j4 * 4]);
        float4 w2 = *reinterpret_cast<const float4*>(&g_ew1[2 * 16 + j4 * 4]);
        float y0 = TWO_L2E * fmaf(temp, w2.x, fmaf(S_water, w1.x, fmaf(S_snow, w0.x, b4.x)));
        float y1 = TWO_L2E * fmaf(temp, w2.y, fmaf(S_water, w1.y, fmaf(S_snow, w0.y, b4.y)));
        float y2 = TWO_L2E * fmaf(temp, w2.z, fmaf(S_water, w1.z, fmaf(S_snow, w0.z, b4.z)));
        float y3 = TWO_L2E * fmaf(temp, w2.w, fmaf(S_water, w1.w, fmaf(S_snow, w0.w, b4.w)));
        unsigned wl, wh;
        quad_tanh_pack(y0, y1, y2, y3, wl, wh);
        if (j4 < 2) { elo[j4 * 2] = wl; elo[j4 * 2 + 1] = wh; }
        else        { ehi[(j4 - 2) * 2] = wl; ehi[(j4 - 2) * 2 + 1] = wh; }
    }
#pragma unroll
    for (int j4 = 0; j4 < 4; ++j4) {
        float4 b4 = *reinterpret_cast<const float4*>(&g_qb1[j4 * 4]);
        float4 w0 = *reinterpret_cast<const float4*>(&g_qw1[0 * 16 + j4 * 4]);
        float4 w1 = *reinterpret_cast<const float4*>(&g_qw1[1 * 16 + j4 * 4]);
        float y0 = TWO_L2E * fmaf(precp, w1.x, fmaf(S_water, w0.x, b4.x));
        float y1 = TWO_L2E * fmaf(precp, w1.y, fmaf(S_water, w0.y, b4.y));
        float y2 = TWO_L2E * fmaf(precp, w1.z, fmaf(S_water, w0.z, b4.z));
        float y3 = TWO_L2E * fmaf(precp, w1.w, fmaf(S_water, w0.w, b4.w));
        unsigned wl, wh;
        quad_tanh_pack(y0, y1, y2, y3, wl, wh);
        if (j4 < 2) { qlo[j4 * 2] = wl; qlo[j4 * 2 + 1] = wh; }
        else        { qhi[(j4 - 2) * 2] = wl; qhi[(j4 - 2) * 2 + 1] = wh; }
    }

    // distribute to the two 32-sample B blocks
    FragU bae, bbe, baq, bbq;
#pragma unroll
    for (int p = 0; p < 4; ++p) {
        unsigned l = elo[p], h = ehi[p];
        plswap(l, h);
        bae.u[p] = l; bbe.u[p] = h;
        l = qlo[p]; h = qhi[p];
        plswap(l, h);
        baq.u[p] = l; bbq.u[p] = h;
    }

    const float ETs = tail_slim<0>(a2, g_eb2, g_ew3, pinit_e, hi, bae, bbe);
    const float Qs  = tail_slim<8>(a2, g_qb2, g_qw3, pinit_q, hi, baq, bbq);

    // ===== bucket dynamics =====
    const float sw_step = step_fn(S_water);
    const float sp      = step_fn(temp - Tmin);
    const float melt = step_fn(temp - Tmax) * step_fn(S_snow)
                     * fminf(S_snow, Df * (temp - Tmax));
    const float dS1 = (1.0f - sp) * precp - melt;
    const float dS2 = sp * precp + melt
                    - sw_step * fmaf(lday, __builtin_amdgcn_exp2f(ETs),
                                     __builtin_amdgcn_exp2f(Qs));
    return make_float2(dS1, dS2);
}

__global__ __launch_bounds__(256, 4) void hydro_kernel(
    const float* __restrict__ g_t,
    const float* __restrict__ g_S,
    const float* __restrict__ g_precp,
    const float* __restrict__ g_temp,
    const float* __restrict__ g_lday,
    const float* __restrict__ g_ew1, const float* __restrict__ g_eb1,
    const float* __restrict__ g_ew2, const float* __restrict__ g_eb2,
    const float* __restrict__ g_ew3, const float* __restrict__ g_eb3,
    const float* __restrict__ g_qw1, const float* __restrict__ g_qb1,
    const float* __restrict__ g_qw2, const float* __restrict__ g_qb2,
    const float* __restrict__ g_qw3, const float* __restrict__ g_qb3,
    const float* __restrict__ g_Df, const float* __restrict__ g_Tmax,
    const float* __restrict__ g_Tmin,
    float* __restrict__ g_out, int B)
{
    __shared__ __align__(16) float4 s_tbl[TLEN];

    const int tx = threadIdx.x;
    for (int i = tx; i < TLEN; i += 256) {
        s_tbl[i] = make_float4(g_precp[i], g_temp[i], g_lday[i], 0.0f);
    }
    __syncthreads();

    const int lane = tx & 63;
    const int m  = lane & 31;           // A row: <16 -> ET feature m, >=16 -> Q feature m-16
    const bool hi = (lane >> 5) != 0;   // k-group / C-row-half select

    // combined A-fragment (4 VGPRs, one-time scattered loads)
    FragU a2;
    {
        const float* wsrc = (m < 16) ? g_ew2 : g_qw2;
        const int mm = m & 15;
        const int kg8 = hi ? 8 : 0;
#pragma unroll
        for (int p = 0; p < 4; ++p) {
            const int k0 = kg8 + 2 * p, k1 = k0 + 1;
            a2.u[p] = cvt_pk_bf16(TWO_L2E * wsrc[k0 * 16 + mm],
                                  TWO_L2E * wsrc[k1 * 16 + mm]);
        }
    }

    // uniform row-sums of w3 (SGPR-resident), pinit = l2e*(0.5*b3 + sum8(w3 rows))
    float slo_e = 0.0f, shi_e = 0.0f, slo_q = 0.0f, shi_q = 0.0f;
#pragma unroll
    for (int r = 0; r < 8; ++r) {
        const int j0 = (r & 3) + 8 * (r >> 2);
        slo_e += g_ew3[j0]; shi_e += g_ew3[j0 + 4];
        slo_q += g_qw3[j0]; shi_q += g_qw3[j0 + 4];
    }
    const float pinit_e = L2E * fmaf(0.5f, g_eb3[0], hi ? shi_e : slo_e);
    const float pinit_q = L2E * fmaf(0.5f, g_qb3[0], hi ? shi_q : slo_q);

    const float Df   = fminf(fmaxf(g_Df[0],   0.01f), 5.0f);
    const float Tmax = fminf(fmaxf(g_Tmax[0], 0.0f),  3.0f);
    const float Tmin = fminf(fmaxf(g_Tmin[0], -3.0f), 0.0f);

    // two samples per thread: i0 = blk*512 + tx, i1 = i0 + 256
    const int i0 = blockIdx.x * 512 + tx;
    const int i1 = i0 + 256;
    const int c0i = (i0 < B) ? i0 : (B - 1);
    const int c1i = (i1 < B) ? i1 : (B - 1);

    const float tv0 = g_t[c0i];
    const float tv1 = g_t[c1i];
    const float2 Sv0 = reinterpret_cast<const float2*>(g_S)[c0i];
    const float2 Sv1 = reinterpret_cast<const float2*>(g_S)[c1i];

    const float2 r0 = sample_pipeline(tv0, Sv0.x, Sv0.y, s_tbl, a2,
                                      pinit_e, pinit_q, hi, Df, Tmax, Tmin,
                                      g_ew1, g_eb1, g_eb2, g_ew3,
                                      g_qw1, g_qb1, g_qb2, g_qw3);
    const float2 r1 = sample_pipeline(tv1, Sv1.x, Sv1.y, s_tbl, a2,
                                      pinit_e, pinit_q, hi, Df, Tmax, Tmin,
                                      g_ew1, g_eb1, g_eb2, g_ew3,
                                      g_qw1, g_qb1, g_qb2, g_qw3);

    if (i0 < B) reinterpret_cast<float2*>(g_out)[i0] = r0;
    if (i1 < B) reinterpret_cast<float2*>(g_out)[i1] = r1;
}

extern "C" void kernel_launch(void* const* d_in, const int* in_sizes, int n_in,
                              void* d_out, int out_size, void* d_ws, size_t ws_size,
                              hipStream_t stream)
{
    const int B = in_sizes[0];
    const int block = 256;
    const int grid = (B + 511) / 512;
    hipLaunchKernelGGL(hydro_kernel, dim3(grid), dim3(block), 0, stream,
        (const float*)d_in[0],  // t
        (const float*)d_in[1],  // S
        (const float*)d_in[3],  // precp_series
        (const float*)d_in[4],  // temp_series
        (const float*)d_in[5],  // lday_series
        (const float*)d_in[6],  (const float*)d_in[7],
        (const float*)d_in[8],  (const float*)d_in[9],
        (const float*)d_in[10], (const float*)d_in[11],
        (const float*)d_in[12], (const float*)d_in[13],
        (const float*)d_in[14], (const float*)d_in[15],
        (const float*)d_in[16], (const float*)d_in[17],
        (const float*)d_in[21], // Df
        (const float*)d_in[22], // Tmax
        (const float*)d_in[23], // Tmin
        (float*)d_out, B);
}

// Round 9
// 27.831 us; speedup vs baseline: 1.0051x; 1.0051x over previous
//
#include <hip/hip_runtime.h>

#define TLEN 1461
#define L2E      1.44269504088896340736f
#define TWO_L2E  2.88539008177792681472f

typedef __bf16 bf16x8 __attribute__((ext_vector_type(8)));
typedef float f32x16 __attribute__((ext_vector_type(16)));

union FragU { unsigned u[4]; bf16x8 f; };

__device__ __forceinline__ float step_fn(float x) {
    // (tanh(5x)+1)/2 = sigmoid(10x) = 1/(1+exp2(-10*log2e*x))
    float e = __builtin_amdgcn_exp2f(x * -14.4269504088896341f);
    return __builtin_amdgcn_rcpf(1.0f + e);
}
__device__ __forceinline__ unsigned cvt_pk_bf16(float lo, float hi) {
    unsigned r;
    asm("v_cvt_pk_bf16_f32 %0, %1, %2" : "=v"(r) : "v"(lo), "v"(hi));
    return r;
}
__device__ __forceinline__ void plswap(unsigned &a, unsigned &b) {
    asm("v_permlane32_swap_b32 %0, %1" : "+v"(a), "+v"(b));
}
__device__ __forceinline__ float plswap_add(float a, float b) {
    unsigned ua = __float_as_uint(a), ub = __float_as_uint(b);
    plswap(ua, ub);
    return __uint_as_float(ua) + __uint_as_float(ub);
}
// inf-safe: y=+big -> exp2=inf -> rcp=0 -> h=1; y=-big -> rcp(1)=1 -> h=-1
__device__ __forceinline__ float tanh_pre(float y) {
    float s = __builtin_amdgcn_rcpf(1.0f + __builtin_amdgcn_exp2f(y));
    return fmaf(-2.0f, s, 1.0f);
}

// layer2 MFMA + sigma-folded dot, SEQUENTIAL blocks (16 C regs live, not 32).
// Weight constants rematerializable (uniform s_load + cndmask on hi).
template <int BASE>
__device__ __forceinline__ float tail_seq(const FragU a2,
    const float* __restrict__ b2, const float* __restrict__ w3,
    float pinit, bool hi, const FragU ba, const FragU bb)
{
    float p0 = pinit, p1 = pinit;
    {
        f32x16 c;
#pragma unroll
        for (int r = 0; r < 8; ++r) {
            const int j0 = (r & 3) + 8 * (r >> 2);
            c[BASE + r] = TWO_L2E * (hi ? b2[j0 + 4] : b2[j0]);
        }
        c = __builtin_amdgcn_mfma_f32_32x32x16_bf16(a2.f, ba.f, c, 0, 0, 0);
#pragma unroll
        for (int r = 0; r < 8; ++r) {
            const int j0 = (r & 3) + 8 * (r >> 2);
            float w3n = -2.0f * L2E * (hi ? w3[j0 + 4] : w3[j0]);
            float s = __builtin_amdgcn_rcpf(1.0f + __builtin_amdgcn_exp2f(c[BASE + r]));
            p0 = fmaf(w3n, s, p0);
        }
    }
    {
        f32x16 c;
#pragma unroll
        for (int r = 0; r < 8; ++r) {
            const int j0 = (r & 3) + 8 * (r >> 2);
            c[BASE + r] = TWO_L2E * (hi ? b2[j0 + 4] : b2[j0]);
        }
        c = __builtin_amdgcn_mfma_f32_32x32x16_bf16(a2.f, bb.f, c, 0, 0, 0);
#pragma unroll
        for (int r = 0; r < 8; ++r) {
            const int j0 = (r & 3) + 8 * (r >> 2);
            float w3n = -2.0f * L2E * (hi ? w3[j0 + 4] : w3[j0]);
            float s = __builtin_amdgcn_rcpf(1.0f + __builtin_amdgcn_exp2f(c[BASE + r]));
            p1 = fmaf(w3n, s, p1);
        }
    }
    return plswap_add(p0, p1);   // lane gets its own sample's total
}

__global__ __launch_bounds__(256, 8) void hydro_kernel(
    const float* __restrict__ g_t,
    const float* __restrict__ g_S,
    const float* __restrict__ g_precp,
    const float* __restrict__ g_temp,
    const float* __restrict__ g_lday,
    const float* __restrict__ g_ew1, const float* __restrict__ g_eb1,
    const float* __restrict__ g_ew2, const float* __restrict__ g_eb2,
    const float* __restrict__ g_ew3, const float* __restrict__ g_eb3,
    const float* __restrict__ g_qw1, const float* __restrict__ g_qb1,
    const float* __restrict__ g_qw2, const float* __restrict__ g_qb2,
    const float* __restrict__ g_qw3, const float* __restrict__ g_qb3,
    const float* __restrict__ g_Df, const float* __restrict__ g_Tmax,
    const float* __restrict__ g_Tmin,
    float* __restrict__ g_out, int B)
{
    // 17.5 KB LDS (fits >=8 blocks/CU): {precp,temp} pairs + lday
    __shared__ __align__(16) float2 s_pt[TLEN];
    __shared__ __align__(16) float  s_ld[TLEN];

    const int tx = threadIdx.x;
    for (int i = tx; i < TLEN; i += 256) {
        s_pt[i] = make_float2(g_precp[i], g_temp[i]);
        s_ld[i] = g_lday[i];
    }
    __syncthreads();

    const int lane = tx & 63;
    const int m  = lane & 31;           // A row: <16 -> ET feature m, >=16 -> Q feature m-16
    const bool hi = (lane >> 5) != 0;   // k-group / C-row-half select

    // combined A-fragment (4 VGPRs): ET W2 rows 0-15, Q W2 rows 16-31
    FragU a2;
    {
        const float* wsrc = (m < 16) ? g_ew2 : g_qw2;
        const int mm = m & 15;
        const int kg8 = hi ? 8 : 0;
#pragma unroll
        for (int p = 0; p < 4; ++p) {
            const int k0 = kg8 + 2 * p, k1 = k0 + 1;
            a2.u[p] = cvt_pk_bf16(TWO_L2E * wsrc[k0 * 16 + mm],
                                  TWO_L2E * wsrc[k1 * 16 + mm]);
        }
    }

    // pinit = l2e*(0.5*b3 + sum8(w3 rows of this half))   (sigma-fold constant)
    float slo_e = 0.0f, shi_e = 0.0f, slo_q = 0.0f, shi_q = 0.0f;
#pragma unroll
    for (int r = 0; r < 8; ++r) {
        const int j0 = (r & 3) + 8 * (r >> 2);
        slo_e += g_ew3[j0]; shi_e += g_ew3[j0 + 4];
        slo_q += g_qw3[j0]; shi_q += g_qw3[j0 + 4];
    }
    const float pinit_e = L2E * fmaf(0.5f, g_eb3[0], hi ? shi_e : slo_e);
    const float pinit_q = L2E * fmaf(0.5f, g_qb3[0], hi ? shi_q : slo_q);

    const float Df   = fminf(fmaxf(g_Df[0],   0.01f), 5.0f);
    const float Tmax = fminf(fmaxf(g_Tmax[0], 0.0f),  3.0f);
    const float Tmin = fminf(fmaxf(g_Tmin[0], -3.0f), 0.0f);

    // ONE sample per thread
    const int i = blockIdx.x * 256 + tx;
    const int ic = (i < B) ? i : (B - 1);   // clamp: all lanes active for cross-lane ops

    const float tv = g_t[ic];
    const float2 Sv = reinterpret_cast<const float2*>(g_S)[ic];
    const float S_snow = Sv.x, S_water = Sv.y;

    int idx = (int)tv;
    idx = max(0, min(idx, TLEN - 2));
    const float fr = tv - (float)idx;
    const float2 pt0 = s_pt[idx];
    const float2 pt1 = s_pt[idx + 1];
    const float precp = fmaf(fr, pt1.x - pt0.x, pt0.x);
    const float temp  = fmaf(fr, pt1.y - pt0.y, pt0.y);
    const float lday  = fmaf(fr, s_ld[idx + 1] - s_ld[idx], s_ld[idx]);

    // ===== ET: layer1 -> pack -> MFMA tail (fully retired before Q starts) =====
    float ETs;
    {
        unsigned w[8];
#pragma unroll
        for (int j4 = 0; j4 < 4; ++j4) {
            float4 b4 = *reinterpret_cast<const float4*>(&g_eb1[j4 * 4]);
            float4 w0 = *reinterpret_cast<const float4*>(&g_ew1[0 * 16 + j4 * 4]);
            float4 w1 = *reinterpret_cast<const float4*>(&g_ew1[1 * 16 + j4 * 4]);
            float4 w2 = *reinterpret_cast<const float4*>(&g_ew1[2 * 16 + j4 * 4]);
            float h0 = tanh_pre(TWO_L2E * fmaf(temp, w2.x, fmaf(S_water, w1.x, fmaf(S_snow, w0.x, b4.x))));
            float h1 = tanh_pre(TWO_L2E * fmaf(temp, w2.y, fmaf(S_water, w1.y, fmaf(S_snow, w0.y, b4.y))));
            float h2 = tanh_pre(TWO_L2E * fmaf(temp, w2.z, fmaf(S_water, w1.z, fmaf(S_snow, w0.z, b4.z))));
            float h3 = tanh_pre(TWO_L2E * fmaf(temp, w2.w, fmaf(S_water, w1.w, fmaf(S_snow, w0.w, b4.w))));
            w[2 * j4]     = cvt_pk_bf16(h0, h1);
            w[2 * j4 + 1] = cvt_pk_bf16(h2, h3);
        }
        FragU ba, bb;
#pragma unroll
        for (int p = 0; p < 4; ++p) {
            unsigned a = w[p], b = w[p + 4];
            plswap(a, b);
            ba.u[p] = a; bb.u[p] = b;
        }
        ETs = tail_seq<0>(a2, g_eb2, g_ew3, pinit_e, hi, ba, bb);
    }

    // ===== Q: layer1 -> pack -> MFMA tail =====
    float Qs;
    {
        unsigned w[8];
#pragma unroll
        for (int j4 = 0; j4 < 4; ++j4) {
            float4 b4 = *reinterpret_cast<const float4*>(&g_qb1[j4 * 4]);
            float4 w0 = *reinterpret_cast<const float4*>(&g_qw1[0 * 16 + j4 * 4]);
            float4 w1 = *reinterpret_cast<const float4*>(&g_qw1[1 * 16 + j4 * 4]);
            float h0 = tanh_pre(TWO_L2E * fmaf(precp, w1.x, fmaf(S_water, w0.x, b4.x)));
            float h1 = tanh_pre(TWO_L2E * fmaf(precp, w1.y, fmaf(S_water, w0.y, b4.y)));
            float h2 = tanh_pre(TWO_L2E * fmaf(precp, w1.z, fmaf(S_water, w0.z, b4.z)));
            float h3 = tanh_pre(TWO_L2E * fmaf(precp, w1.w, fmaf(S_water, w0.w, b4.w)));
            w[2 * j4]     = cvt_pk_bf16(h0, h1);
            w[2 * j4 + 1] = cvt_pk_bf16(h2, h3);
        }
        FragU ba, bb;
#pragma unroll
        for (int p = 0; p < 4; ++p) {
            unsigned a = w[p], b = w[p + 4];
            plswap(a, b);
            ba.u[p] = a; bb.u[p] = b;
        }
        Qs = tail_seq<8>(a2, g_qb2, g_qw3, pinit_q, hi, ba, bb);
    }

    // ===== bucket dynamics =====
    const float sw_step = step_fn(S_water);
    const float sp      = step_fn(temp - Tmin);
    const float melt = step_fn(temp - Tmax) * step_fn(S_snow)
                     * fminf(S_snow, Df * (temp - Tmax));
    const float dS1 = (1.0f - sp) * precp - melt;
    const float dS2 = sp * precp + melt
                    - sw_step * fmaf(lday, __builtin_amdgcn_exp2f(ETs),
                                     __builtin_amdgcn_exp2f(Qs));

    if (i < B) {
        reinterpret_cast<float2*>(g_out)[i] = make_float2(dS1, dS2);
    }
}

extern "C" void kernel_launch(void* const* d_in, const int* in_sizes, int n_in,
                              void* d_out, int out_size, void* d_ws, size_t ws_size,
                              hipStream_t stream)
{
    const int B = in_sizes[0];
    const int block = 256;
    const int grid = (B + block - 1) / block;
    hipLaunchKernelGGL(hydro_kernel, dim3(grid), dim3(block), 0, stream,
        (const float*)d_in[0],  // t
        (const float*)d_in[1],  // S
        (const float*)d_in[3],  // precp_series
        (const float*)d_in[4],  // temp_series
        (const float*)d_in[5],  // lday_series
        (const float*)d_in[6],  (const float*)d_in[7],
        (const float*)d_in[8],  (const float*)d_in[9],
        (const float*)d_in[10], (const float*)d_in[11],
        (const float*)d_in[12], (const float*)d_in[13],
        (const float*)d_in[14], (const float*)d_in[15],
        (const float*)d_in[16], (const float*)d_in[17],
        (const float*)d_in[21], // Df
        (const float*)d_in[22], // Tmax
        (const float*)d_in[23], // Tmin
        (float*)d_out, B);
}

// Round 10
// 26.415 us; speedup vs baseline: 1.0590x; 1.0536x over previous
//
#include <hip/hip_runtime.h>

#define TLEN 1461
#define L2E      1.44269504088896340736f
#define TWO_L2E  2.88539008177792681472f

typedef __bf16 bf16x8 __attribute__((ext_vector_type(8)));
typedef float f32x16 __attribute__((ext_vector_type(16)));

union FragU { unsigned u[4]; bf16x8 f; };

__device__ __forceinline__ float step_fn(float x) {
    // (tanh(5x)+1)/2 = sigmoid(10x) = 1/(1+exp2(-10*log2e*x))
    float e = __builtin_amdgcn_exp2f(x * -14.4269504088896341f);
    return __builtin_amdgcn_rcpf(1.0f + e);
}
__device__ __forceinline__ unsigned cvt_pk_bf16(float lo, float hi) {
    unsigned r;
    asm("v_cvt_pk_bf16_f32 %0, %1, %2" : "=v"(r) : "v"(lo), "v"(hi));
    return r;
}
__device__ __forceinline__ void plswap(unsigned &a, unsigned &b) {
    asm("v_permlane32_swap_b32 %0, %1" : "+v"(a), "+v"(b));
}
__device__ __forceinline__ float plswap_add(float a, float b) {
    unsigned ua = __float_as_uint(a), ub = __float_as_uint(b);
    plswap(ua, ub);
    return __uint_as_float(ua) + __uint_as_float(ub);
}
// inf-safe: y=+big -> exp2=inf -> rcp=0 -> h=1; y=-big -> rcp(1)=1 -> h=-1
__device__ __forceinline__ float tanh_pre(float y) {
    float s = __builtin_amdgcn_rcpf(1.0f + __builtin_amdgcn_exp2f(y));
    return fmaf(-2.0f, s, 1.0f);
}

// layer2 MFMA + sigma-folded dot, SEQUENTIAL blocks (16 C regs live, not 32).
// Weight constants rematerializable (uniform s_load + cndmask on hi).
template <int BASE>
__device__ __forceinline__ float tail_seq(const FragU a2,
    const float* __restrict__ b2, const float* __restrict__ w3,
    float pinit, bool hi, const FragU ba, const FragU bb)
{
    float p0 = pinit, p1 = pinit;
    {
        f32x16 c;
#pragma unroll
        for (int r = 0; r < 8; ++r) {
            const int j0 = (r & 3) + 8 * (r >> 2);
            c[BASE + r] = TWO_L2E * (hi ? b2[j0 + 4] : b2[j0]);
        }
        c = __builtin_amdgcn_mfma_f32_32x32x16_bf16(a2.f, ba.f, c, 0, 0, 0);
#pragma unroll
        for (int r = 0; r < 8; ++r) {
            const int j0 = (r & 3) + 8 * (r >> 2);
            float w3n = -2.0f * L2E * (hi ? w3[j0 + 4] : w3[j0]);
            float s = __builtin_amdgcn_rcpf(1.0f + __builtin_amdgcn_exp2f(c[BASE + r]));
            p0 = fmaf(w3n, s, p0);
        }
    }
    {
        f32x16 c;
#pragma unroll
        for (int r = 0; r < 8; ++r) {
            const int j0 = (r & 3) + 8 * (r >> 2);
            c[BASE + r] = TWO_L2E * (hi ? b2[j0 + 4] : b2[j0]);
        }
        c = __builtin_amdgcn_mfma_f32_32x32x16_bf16(a2.f, bb.f, c, 0, 0, 0);
#pragma unroll
        for (int r = 0; r < 8; ++r) {
            const int j0 = (r & 3) + 8 * (r >> 2);
            float w3n = -2.0f * L2E * (hi ? w3[j0 + 4] : w3[j0]);
            float s = __builtin_amdgcn_rcpf(1.0f + __builtin_amdgcn_exp2f(c[BASE + r]));
            p1 = fmaf(w3n, s, p1);
        }
    }
    return plswap_add(p0, p1);   // lane gets its own sample's total
}

__global__ __launch_bounds__(256, 8) void hydro_kernel(
    const float* __restrict__ g_t,
    const float* __restrict__ g_S,
    const float* __restrict__ g_precp,
    const float* __restrict__ g_temp,
    const float* __restrict__ g_lday,
    const float* __restrict__ g_ew1, const float* __restrict__ g_eb1,
    const float* __restrict__ g_ew2, const float* __restrict__ g_eb2,
    const float* __restrict__ g_ew3, const float* __restrict__ g_eb3,
    const float* __restrict__ g_qw1, const float* __restrict__ g_qb1,
    const float* __restrict__ g_qw2, const float* __restrict__ g_qb2,
    const float* __restrict__ g_qw3, const float* __restrict__ g_qb3,
    const float* __restrict__ g_Df, const float* __restrict__ g_Tmax,
    const float* __restrict__ g_Tmin,
    float* __restrict__ g_out, int B)
{
    // NO LDS, NO barrier: the 17.5 KB series data lives in L1/L2 and is
    // gathered per-lane. Deletes the per-block fill+syncthreads prologue.
    const int tx = threadIdx.x;
    const int lane = tx & 63;
    const int m  = lane & 31;           // A row: <16 -> ET feature m, >=16 -> Q feature m-16
    const bool hi = (lane >> 5) != 0;   // k-group / C-row-half select

    // combined A-fragment (4 VGPRs): ET W2 rows 0-15, Q W2 rows 16-31
    FragU a2;
    {
        const float* wsrc = (m < 16) ? g_ew2 : g_qw2;
        const int mm = m & 15;
        const int kg8 = hi ? 8 : 0;
#pragma unroll
        for (int p = 0; p < 4; ++p) {
            const int k0 = kg8 + 2 * p, k1 = k0 + 1;
            a2.u[p] = cvt_pk_bf16(TWO_L2E * wsrc[k0 * 16 + mm],
                                  TWO_L2E * wsrc[k1 * 16 + mm]);
        }
    }

    // pinit = l2e*(0.5*b3 + sum8(w3 rows of this half))   (sigma-fold constant)
    float slo_e = 0.0f, shi_e = 0.0f, slo_q = 0.0f, shi_q = 0.0f;
#pragma unroll
    for (int r = 0; r < 8; ++r) {
        const int j0 = (r & 3) + 8 * (r >> 2);
        slo_e += g_ew3[j0]; shi_e += g_ew3[j0 + 4];
        slo_q += g_qw3[j0]; shi_q += g_qw3[j0 + 4];
    }
    const float pinit_e = L2E * fmaf(0.5f, g_eb3[0], hi ? shi_e : slo_e);
    const float pinit_q = L2E * fmaf(0.5f, g_qb3[0], hi ? shi_q : slo_q);

    const float Df   = fminf(fmaxf(g_Df[0],   0.01f), 5.0f);
    const float Tmax = fminf(fmaxf(g_Tmax[0], 0.0f),  3.0f);
    const float Tmin = fminf(fmaxf(g_Tmin[0], -3.0f), 0.0f);

    // ONE sample per thread
    const int i = blockIdx.x * 256 + tx;
    const int ic = (i < B) ? i : (B - 1);   // clamp: all lanes active for cross-lane ops

    const float tv = g_t[ic];
    const float2 Sv = reinterpret_cast<const float2*>(g_S)[ic];
    const float S_snow = Sv.x, S_water = Sv.y;

    int idx = (int)tv;
    idx = max(0, min(idx, TLEN - 2));
    const float fr = tv - (float)idx;
    // per-lane global gathers, L1-resident after warmup
    const float p0v = g_precp[idx], p1v = g_precp[idx + 1];
    const float t0v = g_temp[idx],  t1v = g_temp[idx + 1];
    const float l0v = g_lday[idx],  l1v = g_lday[idx + 1];
    const float precp = fmaf(fr, p1v - p0v, p0v);
    const float temp  = fmaf(fr, t1v - t0v, t0v);
    const float lday  = fmaf(fr, l1v - l0v, l0v);

    // ===== ET: layer1 -> pack -> MFMA tail (fully retired before Q starts) =====
    float ETs;
    {
        unsigned w[8];
#pragma unroll
        for (int j4 = 0; j4 < 4; ++j4) {
            float4 b4 = *reinterpret_cast<const float4*>(&g_eb1[j4 * 4]);
            float4 w0 = *reinterpret_cast<const float4*>(&g_ew1[0 * 16 + j4 * 4]);
            float4 w1 = *reinterpret_cast<const float4*>(&g_ew1[1 * 16 + j4 * 4]);
            float4 w2 = *reinterpret_cast<const float4*>(&g_ew1[2 * 16 + j4 * 4]);
            float h0 = tanh_pre(TWO_L2E * fmaf(temp, w2.x, fmaf(S_water, w1.x, fmaf(S_snow, w0.x, b4.x))));
            float h1 = tanh_pre(TWO_L2E * fmaf(temp, w2.y, fmaf(S_water, w1.y, fmaf(S_snow, w0.y, b4.y))));
            float h2 = tanh_pre(TWO_L2E * fmaf(temp, w2.z, fmaf(S_water, w1.z, fmaf(S_snow, w0.z, b4.z))));
            float h3 = tanh_pre(TWO_L2E * fmaf(temp, w2.w, fmaf(S_water, w1.w, fmaf(S_snow, w0.w, b4.w))));
            w[2 * j4]     = cvt_pk_bf16(h0, h1);
            w[2 * j4 + 1] = cvt_pk_bf16(h2, h3);
        }
        FragU ba, bb;
#pragma unroll
        for (int p = 0; p < 4; ++p) {
            unsigned a = w[p], b = w[p + 4];
            plswap(a, b);
            ba.u[p] = a; bb.u[p] = b;
        }
        ETs = tail_seq<0>(a2, g_eb2, g_ew3, pinit_e, hi, ba, bb);
    }

    // ===== Q: layer1 -> pack -> MFMA tail =====
    float Qs;
    {
        unsigned w[8];
#pragma unroll
        for (int j4 = 0; j4 < 4; ++j4) {
            float4 b4 = *reinterpret_cast<const float4*>(&g_qb1[j4 * 4]);
            float4 w0 = *reinterpret_cast<const float4*>(&g_qw1[0 * 16 + j4 * 4]);
            float4 w1 = *reinterpret_cast<const float4*>(&g_qw1[1 * 16 + j4 * 4]);
            float h0 = tanh_pre(TWO_L2E * fmaf(precp, w1.x, fmaf(S_water, w0.x, b4.x)));
            float h1 = tanh_pre(TWO_L2E * fmaf(precp, w1.y, fmaf(S_water, w0.y, b4.y)));
            float h2 = tanh_pre(TWO_L2E * fmaf(precp, w1.z, fmaf(S_water, w0.z, b4.z)));
            float h3 = tanh_pre(TWO_L2E * fmaf(precp, w1.w, fmaf(S_water, w0.w, b4.w)));
            w[2 * j4]     = cvt_pk_bf16(h0, h1);
            w[2 * j4 + 1] = cvt_pk_bf16(h2, h3);
        }
        FragU ba, bb;
#pragma unroll
        for (int p = 0; p < 4; ++p) {
            unsigned a = w[p], b = w[p + 4];
            plswap(a, b);
            ba.u[p] = a; bb.u[p] = b;
        }
        Qs = tail_seq<8>(a2, g_qb2, g_qw3, pinit_q, hi, ba, bb);
    }

    // ===== bucket dynamics =====
    const float sw_step = step_fn(S_water);
    const float sp      = step_fn(temp - Tmin);
    const float melt = step_fn(temp - Tmax) * step_fn(S_snow)
                     * fminf(S_snow, Df * (temp - Tmax));
    const float dS1 = (1.0f - sp) * precp - melt;
    const float dS2 = sp * precp + melt
                    - sw_step * fmaf(lday, __builtin_amdgcn_exp2f(ETs),
                                     __builtin_amdgcn_exp2f(Qs));

    if (i < B) {
        reinterpret_cast<float2*>(g_out)[i] = make_float2(dS1, dS2);
    }
}

extern "C" void kernel_launch(void* const* d_in, const int* in_sizes, int n_in,
                              void* d_out, int out_size, void* d_ws, size_t ws_size,
                              hipStream_t stream)
{
    const int B = in_sizes[0];
    const int block = 256;
    const int grid = (B + block - 1) / block;
    hipLaunchKernelGGL(hydro_kernel, dim3(grid), dim3(block), 0, stream,
        (const float*)d_in[0],  // t
        (const float*)d_in[1],  // S
        (const float*)d_in[3],  // precp_series
        (const float*)d_in[4],  // temp_series
        (const float*)d_in[5],  // lday_series
        (const float*)d_in[6],  (const float*)d_in[7],
        (const float*)d_in[8],  (const float*)d_in[9],
        (const float*)d_in[10], (const float*)d_in[11],
        (const float*)d_in[12], (const float*)d_in[13],
        (const float*)d_in[14], (const float*)d_in[15],
        (const float*)d_in[16], (const float*)d_in[17],
        (const float*)d_in[21], // Df
        (const float*)d_in[22], // Tmax
        (const float*)d_in[23], // Tmin
        (float*)d_out, B);
}

// Round 11
// 26.327 us; speedup vs baseline: 1.0625x; 1.0033x over previous
//
#include <hip/hip_runtime.h>

#define TLEN 1461
#define L2E      1.44269504088896340736f
#define TWO_L2E  2.88539008177792681472f
#define NL2E10  -14.4269504088896341f

typedef __bf16 bf16x8 __attribute__((ext_vector_type(8)));
typedef float f32x16 __attribute__((ext_vector_type(16)));

union FragU { unsigned u[4]; bf16x8 f; };

__device__ __forceinline__ unsigned cvt_pk_bf16(float lo, float hi) {
    unsigned r;
    asm("v_cvt_pk_bf16_f32 %0, %1, %2" : "=v"(r) : "v"(lo), "v"(hi));
    return r;
}
__device__ __forceinline__ void plswap(unsigned &a, unsigned &b) {
    asm("v_permlane32_swap_b32 %0, %1" : "+v"(a), "+v"(b));
}
__device__ __forceinline__ float plswap_add(float a, float b) {
    unsigned ua = __float_as_uint(a), ub = __float_as_uint(b);
    plswap(ua, ub);
    return __uint_as_float(ua) + __uint_as_float(ub);
}

// 4 pre-activations y=2*log2e*x -> tanh, ONE rcp per 4 (clamp +-30: tanh
// saturated there, and 4 exp2(30)'s product = 2^120 stays finite)
__device__ __forceinline__ void quad_tanh_pack(float y0, float y1, float y2, float y3,
                                               unsigned &wlo, unsigned &whi) {
    y0 = fminf(fmaxf(y0, -30.0f), 30.0f);
    y1 = fminf(fmaxf(y1, -30.0f), 30.0f);
    y2 = fminf(fmaxf(y2, -30.0f), 30.0f);
    y3 = fminf(fmaxf(y3, -30.0f), 30.0f);
    float d0 = 1.0f + __builtin_amdgcn_exp2f(y0);
    float d1 = 1.0f + __builtin_amdgcn_exp2f(y1);
    float d2 = 1.0f + __builtin_amdgcn_exp2f(y2);
    float d3 = 1.0f + __builtin_amdgcn_exp2f(y3);
    float Pab = d0 * d1, Pcd = d2 * d3;
    float R = __builtin_amdgcn_rcpf(Pab * Pcd);
    float RPcd = Pcd * R;   // = 1/(d0 d1)
    float RPab = Pab * R;   // = 1/(d2 d3)
    float t0 = d1 * RPcd, t1 = d0 * RPcd;   // sigma_i = 1/d_i
    float t2 = d3 * RPab, t3 = d2 * RPab;
    float h0 = fmaf(-2.0f, t0, 1.0f), h1 = fmaf(-2.0f, t1, 1.0f);
    float h2 = fmaf(-2.0f, t2, 1.0f), h3 = fmaf(-2.0f, t3, 1.0f);
    wlo = cvt_pk_bf16(h0, h1);
    whi = cvt_pk_bf16(h2, h3);
}

// sum_i w[i]*sigma(y[i]) with ONE rcp; no clamp (|y|<=~25 here, product < 2^126)
__device__ __forceinline__ float quad_wsum_raw(float y0, float y1, float y2, float y3,
                                               float w0, float w1, float w2, float w3) {
    float d0 = 1.0f + __builtin_amdgcn_exp2f(y0);
    float d1 = 1.0f + __builtin_amdgcn_exp2f(y1);
    float d2 = 1.0f + __builtin_amdgcn_exp2f(y2);
    float d3 = 1.0f + __builtin_amdgcn_exp2f(y3);
    float Pab = d0 * d1, Pcd = d2 * d3;
    float R = __builtin_amdgcn_rcpf(Pab * Pcd);
    float N1 = fmaf(w1, d0, w0 * d1);
    float N2 = fmaf(w3, d2, w2 * d3);
    return fmaf(N2, Pab, N1 * Pcd) * R;
}

// layer2 MFMA + sigma-folded dot, sequential blocks (16 C regs live).
// Weight constants rematerializable (uniform s_load + cndmask on hi).
// p = pinit - 2*l2e * sum(w3_raw * sigma)
template <int BASE>
__device__ __forceinline__ float tail_seq(const FragU a2,
    const float* __restrict__ b2, const float* __restrict__ w3,
    float pinit, bool hi, const FragU ba, const FragU bb)
{
    float w3s[8];
#pragma unroll
    for (int r = 0; r < 8; ++r) {
        const int j0 = (r & 3) + 8 * (r >> 2);
        w3s[r] = hi ? w3[j0 + 4] : w3[j0];
    }
    float p0, p1;
    {
        f32x16 c;
#pragma unroll
        for (int r = 0; r < 8; ++r) {
            const int j0 = (r & 3) + 8 * (r >> 2);
            c[BASE + r] = TWO_L2E * (hi ? b2[j0 + 4] : b2[j0]);
        }
        c = __builtin_amdgcn_mfma_f32_32x32x16_bf16(a2.f, ba.f, c, 0, 0, 0);
        float q = quad_wsum_raw(c[BASE + 0], c[BASE + 1], c[BASE + 2], c[BASE + 3],
                                w3s[0], w3s[1], w3s[2], w3s[3])
                + quad_wsum_raw(c[BASE + 4], c[BASE + 5], c[BASE + 6], c[BASE + 7],
                                w3s[4], w3s[5], w3s[6], w3s[7]);
        p0 = fmaf(-2.0f * L2E, q, pinit);
    }
    {
        f32x16 c;
#pragma unroll
        for (int r = 0; r < 8; ++r) {
            const int j0 = (r & 3) + 8 * (r >> 2);
            c[BASE + r] = TWO_L2E * (hi ? b2[j0 + 4] : b2[j0]);
        }
        c = __builtin_amdgcn_mfma_f32_32x32x16_bf16(a2.f, bb.f, c, 0, 0, 0);
        float q = quad_wsum_raw(c[BASE + 0], c[BASE + 1], c[BASE + 2], c[BASE + 3],
                                w3s[0], w3s[1], w3s[2], w3s[3])
                + quad_wsum_raw(c[BASE + 4], c[BASE + 5], c[BASE + 6], c[BASE + 7],
                                w3s[4], w3s[5], w3s[6], w3s[7]);
        p1 = fmaf(-2.0f * L2E, q, pinit);
    }
    return plswap_add(p0, p1);   // lane gets its own sample's total
}

__global__ __launch_bounds__(256, 8) void hydro_kernel(
    const float* __restrict__ g_t,
    const float* __restrict__ g_S,
    const float* __restrict__ g_precp,
    const float* __restrict__ g_temp,
    const float* __restrict__ g_lday,
    const float* __restrict__ g_ew1, const float* __restrict__ g_eb1,
    const float* __restrict__ g_ew2, const float* __restrict__ g_eb2,
    const float* __restrict__ g_ew3, const float* __restrict__ g_eb3,
    const float* __restrict__ g_qw1, const float* __restrict__ g_qb1,
    const float* __restrict__ g_qw2, const float* __restrict__ g_qb2,
    const float* __restrict__ g_qw3, const float* __restrict__ g_qb3,
    const float* __restrict__ g_Df, const float* __restrict__ g_Tmax,
    const float* __restrict__ g_Tmin,
    float* __restrict__ g_out, int B)
{
    const int tx = threadIdx.x;
    const int lane = tx & 63;
    const int m  = lane & 31;           // A row: <16 -> ET feature m, >=16 -> Q feature m-16
    const bool hi = (lane >> 5) != 0;   // k-group / C-row-half select

    // combined A-fragment (4 VGPRs): ET W2 rows 0-15, Q W2 rows 16-31
    FragU a2;
    {
        const float* wsrc = (m < 16) ? g_ew2 : g_qw2;
        const int mm = m & 15;
        const int kg8 = hi ? 8 : 0;
#pragma unroll
        for (int p = 0; p < 4; ++p) {
            const int k0 = kg8 + 2 * p, k1 = k0 + 1;
            a2.u[p] = cvt_pk_bf16(TWO_L2E * wsrc[k0 * 16 + mm],
                                  TWO_L2E * wsrc[k1 * 16 + mm]);
        }
    }

    // pinit = l2e*(0.5*b3 + sum8(w3 rows of this half))   (sigma-fold constant)
    float slo_e = 0.0f, shi_e = 0.0f, slo_q = 0.0f, shi_q = 0.0f;
#pragma unroll
    for (int r = 0; r < 8; ++r) {
        const int j0 = (r & 3) + 8 * (r >> 2);
        slo_e += g_ew3[j0]; shi_e += g_ew3[j0 + 4];
        slo_q += g_qw3[j0]; shi_q += g_qw3[j0 + 4];
    }
    const float pinit_e = L2E * fmaf(0.5f, g_eb3[0], hi ? shi_e : slo_e);
    const float pinit_q = L2E * fmaf(0.5f, g_qb3[0], hi ? shi_q : slo_q);

    const float Df   = fminf(fmaxf(g_Df[0],   0.01f), 5.0f);
    const float Tmax = fminf(fmaxf(g_Tmax[0], 0.0f),  3.0f);
    const float Tmin = fminf(fmaxf(g_Tmin[0], -3.0f), 0.0f);

    // ONE sample per thread
    const int i = blockIdx.x * 256 + tx;
    const int ic = (i < B) ? i : (B - 1);   // clamp: all lanes active for cross-lane ops

    const float tv = g_t[ic];
    const float2 Sv = reinterpret_cast<const float2*>(g_S)[ic];
    const float S_snow = Sv.x, S_water = Sv.y;

    int idx = (int)tv;
    idx = max(0, min(idx, TLEN - 2));
    const float fr = tv - (float)idx;
    // per-lane global gathers, L1-resident after warmup
    const float p0v = g_precp[idx], p1v = g_precp[idx + 1];
    const float t0v = g_temp[idx],  t1v = g_temp[idx + 1];
    const float l0v = g_lday[idx],  l1v = g_lday[idx + 1];
    const float precp = fmaf(fr, p1v - p0v, p0v);
    const float temp  = fmaf(fr, t1v - t0v, t0v);
    const float lday  = fmaf(fr, l1v - l0v, l0v);

    // ===== ET: layer1 -> pack -> MFMA tail =====
    float ETs;
    {
        unsigned w[8];
#pragma unroll
        for (int j4 = 0; j4 < 4; ++j4) {
            float4 b4 = *reinterpret_cast<const float4*>(&g_eb1[j4 * 4]);
            float4 w0 = *reinterpret_cast<const float4*>(&g_ew1[0 * 16 + j4 * 4]);
            float4 w1 = *reinterpret_cast<const float4*>(&g_ew1[1 * 16 + j4 * 4]);
            float4 w2 = *reinterpret_cast<const float4*>(&g_ew1[2 * 16 + j4 * 4]);
            float y0 = TWO_L2E * fmaf(temp, w2.x, fmaf(S_water, w1.x, fmaf(S_snow, w0.x, b4.x)));
            float y1 = TWO_L2E * fmaf(temp, w2.y, fmaf(S_water, w1.y, fmaf(S_snow, w0.y, b4.y)));
            float y2 = TWO_L2E * fmaf(temp, w2.z, fmaf(S_water, w1.z, fmaf(S_snow, w0.z, b4.z)));
            float y3 = TWO_L2E * fmaf(temp, w2.w, fmaf(S_water, w1.w, fmaf(S_snow, w0.w, b4.w)));
            unsigned wl, wh;
            quad_tanh_pack(y0, y1, y2, y3, wl, wh);
            w[2 * j4]     = wl;
            w[2 * j4 + 1] = wh;
        }
        FragU ba, bb;
#pragma unroll
        for (int p = 0; p < 4; ++p) {
            unsigned a = w[p], b = w[p + 4];
            plswap(a, b);
            ba.u[p] = a; bb.u[p] = b;
        }
        ETs = tail_seq<0>(a2, g_eb2, g_ew3, pinit_e, hi, ba, bb);
    }

    // ===== Q: layer1 -> pack -> MFMA tail =====
    float Qs;
    {
        unsigned w[8];
#pragma unroll
        for (int j4 = 0; j4 < 4; ++j4) {
            float4 b4 = *reinterpret_cast<const float4*>(&g_qb1[j4 * 4]);
            float4 w0 = *reinterpret_cast<const float4*>(&g_qw1[0 * 16 + j4 * 4]);
            float4 w1 = *reinterpret_cast<const float4*>(&g_qw1[1 * 16 + j4 * 4]);
            float y0 = TWO_L2E * fmaf(precp, w1.x, fmaf(S_water, w0.x, b4.x));
            float y1 = TWO_L2E * fmaf(precp, w1.y, fmaf(S_water, w0.y, b4.y));
            float y2 = TWO_L2E * fmaf(precp, w1.z, fmaf(S_water, w0.z, b4.z));
            float y3 = TWO_L2E * fmaf(precp, w1.w, fmaf(S_water, w0.w, b4.w));
            unsigned wl, wh;
            quad_tanh_pack(y0, y1, y2, y3, wl, wh);
            w[2 * j4]     = wl;
            w[2 * j4 + 1] = wh;
        }
        FragU ba, bb;
#pragma unroll
        for (int p = 0; p < 4; ++p) {
            unsigned a = w[p], b = w[p + 4];
            plswap(a, b);
            ba.u[p] = a; bb.u[p] = b;
        }
        Qs = tail_seq<8>(a2, g_qb2, g_qw3, pinit_q, hi, ba, bb);
    }

    // ===== bucket dynamics: 4 steps share ONE rcp (clamp +-31 keeps product finite) =====
    float ya = fminf(fmaxf(NL2E10 * S_water,       -31.0f), 31.0f);
    float yb = fminf(fmaxf(NL2E10 * (temp - Tmin), -31.0f), 31.0f);
    float yc = fminf(fmaxf(NL2E10 * (temp - Tmax), -31.0f), 31.0f);
    float yd = fminf(fmaxf(NL2E10 * S_snow,        -31.0f), 31.0f);
    float da = 1.0f + __builtin_amdgcn_exp2f(ya);
    float db = 1.0f + __builtin_amdgcn_exp2f(yb);
    float dc = 1.0f + __builtin_amdgcn_exp2f(yc);
    float dd = 1.0f + __builtin_amdgcn_exp2f(yd);
    float Pab = da * db, Pcd = dc * dd;
    float R = __builtin_amdgcn_rcpf(Pab * Pcd);
    float RPcd = Pcd * R, RPab = Pab * R;
    const float sw_step = db * RPcd;   // sigma(ya) = 1/da
    const float sp      = da * RPcd;   // step(temp - Tmin)
    const float st_tmax = dd * RPab;   // step(temp - Tmax)
    const float st_snow = dc * RPab;   // step(S_snow)

    const float melt = st_tmax * st_snow * fminf(S_snow, Df * (temp - Tmax));
    const float dS1 = (1.0f - sp) * precp - melt;
    const float dS2 = sp * precp + melt
                    - sw_step * fmaf(lday, __builtin_amdgcn_exp2f(ETs),
                                     __builtin_amdgcn_exp2f(Qs));

    if (i < B) {
        reinterpret_cast<float2*>(g_out)[i] = make_float2(dS1, dS2);
    }
}

extern "C" void kernel_launch(void* const* d_in, const int* in_sizes, int n_in,
                              void* d_out, int out_size, void* d_ws, size_t ws_size,
                              hipStream_t stream)
{
    const int B = in_sizes[0];
    const int block = 256;
    const int grid = (B + block - 1) / block;
    hipLaunchKernelGGL(hydro_kernel, dim3(grid), dim3(block), 0, stream,
        (const float*)d_in[0],  // t
        (const float*)d_in[1],  // S
        (const float*)d_in[3],  // precp_series
        (const float*)d_in[4],  // temp_series
        (const float*)d_in[5],  // lday_series
        (const float*)d_in[6],  (const float*)d_in[7],
        (const float*)d_in[8],  (const float*)d_in[9],
        (const float*)d_in[10], (const float*)d_in[11],
        (const float*)d_in[12], (const float*)d_in[13],
        (const float*)d_in[14], (const float*)d_in[15],
        (const float*)d_in[16], (const float*)d_in[17],
        (const float*)d_in[21], // Df
        (const float*)d_in[22], // Tmax
        (const float*)d_in[23], // Tmin
        (float*)d_out, B);
}